// Round 7
// baseline (73.302 us; speedup 1.0000x reference)
//
#include <hip/hip_runtime.h>
#include <hip/hip_fp16.h>
#include <cstdint>
#include <cstddef>

#define B_ 8
#define N_ 256
#define D_ 128
#define H_ 128
#define K_ 8

typedef _Float16 f16x8 __attribute__((ext_vector_type(8)));
typedef float    f32x4 __attribute__((ext_vector_type(4)));

static __device__ __forceinline__ unsigned packh2(float lo, float hi) {
    unsigned a = __half_as_ushort(__float2half(lo));
    unsigned b = __half_as_ushort(__float2half(hi));
    return a | (b << 16);
}

// ---------------------------------------------------------------------------
// prep_all: [0,256): Eh = fp16(E)
//           [256,320): Wh[k][c][d] = fp16( W1[k][(c<128? d:128+d)][c&127] )
//           320: mW = sign(wd), wdaW = 0.5*|wd|, consts = {b2d, w3d, w3b}
// ---------------------------------------------------------------------------
__global__ __launch_bounds__(256) void prep_all(
        const float* __restrict__ E, const float* __restrict__ W1,
        const float* __restrict__ W2, const float* __restrict__ b2,
        const float* __restrict__ W3, const float* __restrict__ b3,
        __half* __restrict__ Eh, __half* __restrict__ Wh,
        float* __restrict__ mW, float* __restrict__ wdaW,
        float* __restrict__ consts) {
    __shared__ float Ws[128][33];
    const int bid = blockIdx.x;
    const int t   = threadIdx.x;

    if (bid < 256) {
        int idx = (bid * 256 + t) * 4;
        float4 v = *(const float4*)&E[idx];
        uint2 o;
        o.x = packh2(v.x, v.y);
        o.y = packh2(v.z, v.w);
        *(uint2*)&Eh[idx] = o;
    } else if (bid < 320) {
        const int kb = bid - 256;
        const int ct = kb & 7;
        const int k  = kb >> 3;
        const int c0 = ct * 32;
        const int ro = (c0 < 128) ? 0 : 128;
        const int h0 = c0 & 127;
        #pragma unroll
        for (int rep = 0; rep < 16; rep++) {
            int idx = rep * 256 + t;
            int d   = idx >> 5;
            int cl  = idx & 31;
            Ws[d][cl] = W1[((size_t)(k * 256 + ro + d)) * H_ + h0 + cl];
        }
        __syncthreads();
        const int cl = t >> 3;   // 0..31
        const int dg = t & 7;    // 0..7 (16 d each)
        __half tmp[16];
        #pragma unroll
        for (int e = 0; e < 16; e++) tmp[e] = __float2half(Ws[dg * 16 + e][cl]);
        *(float4*)&Wh[((size_t)(k * 256 + c0 + cl)) * D_ + dg * 16]     = *(float4*)&tmp[0];
        *(float4*)&Wh[((size_t)(k * 256 + c0 + cl)) * D_ + dg * 16 + 8] = *(float4*)&tmp[8];
    } else {
        for (int idx = t; idx < K_ * H_; idx += 256) {
            float w = W2[idx * 2] - W2[idx * 2 + 1];
            mW[idx]   = copysignf(1.0f, w);
            wdaW[idx] = 0.5f * fabsf(w);
        }
        if (t < K_) {
            consts[t * 4 + 0] = b2[t * 2] - b2[t * 2 + 1];
            consts[t * 4 + 1] = W3[t * 2] - W3[t * 2 + 1];
            consts[t * 4 + 2] = W3[t * 2 + 1] + b3[t];
        }
    }
}

// ---------------------------------------------------------------------------
// fused v3: block = (bk, 128i x 64j tile).
//  stage A (MFMA): his[128][136] fp16 = 0.5*(Ei@W1i + b1)*|wd| ;
//                  hjs[64][132]  f32  = 0.5*(Ej@W1j)*|wd|
//  u/v pass: u_i = dot(his_row, m), v_j = dot(hjs_row, m)   (rank-1 terms)
//  stage B (VALU, 2 ops/h): acc += m_h * |a'_h + b'_h| ; T = b2d + u + v + acc
// ---------------------------------------------------------------------------
__global__ __launch_bounds__(256, 2) void fused_kernel(
        const __half* __restrict__ Eh, const __half* __restrict__ Wh,
        const float* __restrict__ b1, const float* __restrict__ mW,
        const float* __restrict__ wdaW, const float* __restrict__ consts,
        float* __restrict__ out) {
    __shared__ __half his[128 * 136];
    __shared__ float  hjs[64 * 132];
    __shared__ float  mlds[128];
    __shared__ float  wlds[128];
    __shared__ float  ulds[128];
    __shared__ float  vlds[64];

    const int bid = blockIdx.x;
    const int jt  = bid & 3;            // 4 j-tiles of 64
    const int it  = (bid >> 2) & 1;     // 2 i-tiles of 128
    const int bk  = bid >> 3;
    const int k   = bk & (K_ - 1);
    const int b   = bk >> 3;
    const int i0  = it * 128, j0 = jt * 64;
    const int t   = threadIdx.x;
    const int wv   = t >> 6;
    const int lane = t & 63;
    const int lr   = lane & 15, lk = lane >> 4;

    if (t < 128) { mlds[t] = mW[k * H_ + t]; wlds[t] = wdaW[k * H_ + t]; }
    __syncthreads();

    // ---- stage A: produce his(128 rows, fp16) / hjs(64 rows, f32) via MFMA ----
    #pragma unroll
    for (int rb = 0; rb < 3; rb++) {
        const int row16 = wv * 48 + rb * 16;            // 0..176
        const bool isJ  = (row16 >= 128);
        const int rowg  = isJ ? (j0 + row16 - 128) : (i0 + row16);
        const int cbase = isJ ? 128 : 0;

        f16x8 A[4];
        #pragma unroll
        for (int kk = 0; kk < 4; kk++)
            A[kk] = *(const f16x8*)&Eh[
                ((size_t)(b * N_ + rowg + lr)) * D_ + kk * 32 + lk * 8];

        #pragma unroll
        for (int nc = 0; nc < 8; nc++) {
            f16x8 Bf[4];
            #pragma unroll
            for (int kk = 0; kk < 4; kk++)
                Bf[kk] = *(const f16x8*)&Wh[
                    ((size_t)(k * 256 + cbase + nc * 16 + lr)) * D_ + kk * 32 + lk * 8];
            const int hcol = nc * 16 + lr;
            f32x4 acc = {0.f, 0.f, 0.f, 0.f};
            #pragma unroll
            for (int kk = 0; kk < 4; kk++)
                acc = __builtin_amdgcn_mfma_f32_16x16x32_f16(A[kk], Bf[kk], acc, 0, 0, 0);
            const float sc = wlds[hcol];
            if (isJ) {
                #pragma unroll
                for (int q = 0; q < 4; q++)
                    hjs[(row16 - 128 + lk * 4 + q) * 132 + hcol] = acc[q] * sc;
            } else {
                const float bias = b1[k * H_ + hcol];
                #pragma unroll
                for (int q = 0; q < 4; q++)
                    his[(row16 + lk * 4 + q) * 136 + hcol] =
                        __float2half((acc[q] + bias) * sc);
            }
        }
    }
    __syncthreads();

    // ---- u/v pass: rank-1 row dots with m ----
    if (t < 128) {
        float s = 0.f;
        #pragma unroll
        for (int hq = 0; hq < 16; hq++) {
            f16x8 av = *(const f16x8*)&his[t * 136 + hq * 8];
            #pragma unroll
            for (int e = 0; e < 8; e++) s += (float)av[e] * mlds[hq * 8 + e];
        }
        ulds[t] = s;
    } else if (t < 192) {
        const int r = t - 128;
        float s = 0.f;
        #pragma unroll
        for (int hq = 0; hq < 16; hq++) {
            float4 b0 = *(const float4*)&hjs[r * 132 + hq * 8];
            float4 b1v = *(const float4*)&hjs[r * 132 + hq * 8 + 4];
            s += b0.x * mlds[hq * 8 + 0] + b0.y * mlds[hq * 8 + 1]
               + b0.z * mlds[hq * 8 + 2] + b0.w * mlds[hq * 8 + 3]
               + b1v.x * mlds[hq * 8 + 4] + b1v.y * mlds[hq * 8 + 5]
               + b1v.z * mlds[hq * 8 + 6] + b1v.w * mlds[hq * 8 + 7];
        }
        vlds[r] = s;
    }
    __syncthreads();

    // ---- stage B: 2-op inner loop (add + fma-with-abs) ----
    const float b2d = consts[k * 4 + 0];
    const float w3d = consts[k * 4 + 1];
    const float w3b = consts[k * 4 + 2];
    const int tx = t & 15;   // j = j0 + tx + 16c, c in 0..3
    const int ty = t >> 4;   // i = i0 + ty + 16a, a in 0..7

    float acc[8][4];
    #pragma unroll
    for (int a = 0; a < 8; a++)
        #pragma unroll
        for (int c = 0; c < 4; c++) acc[a][c] = 0.f;

    #pragma unroll 2
    for (int hq = 0; hq < 16; hq++) {   // 8 h per iter
        float mv[8];
        *(float4*)&mv[0] = *(const float4*)&mlds[hq * 8];
        *(float4*)&mv[4] = *(const float4*)&mlds[hq * 8 + 4];
        f16x8 Ah[8];
        #pragma unroll
        for (int a = 0; a < 8; a++)
            Ah[a] = *(const f16x8*)&his[(ty + 16 * a) * 136 + hq * 8];
        float Bf[4][8];
        #pragma unroll
        for (int c = 0; c < 4; c++) {
            *(float4*)&Bf[c][0] = *(const float4*)&hjs[(tx + 16 * c) * 132 + hq * 8];
            *(float4*)&Bf[c][4] = *(const float4*)&hjs[(tx + 16 * c) * 132 + hq * 8 + 4];
        }
        #pragma unroll
        for (int e = 0; e < 8; e++) {
            float Ae[8];
            #pragma unroll
            for (int a = 0; a < 8; a++) Ae[a] = (float)Ah[a][e];
            #pragma unroll
            for (int a = 0; a < 8; a++)
                #pragma unroll
                for (int c = 0; c < 4; c++)
                    acc[a][c] = fmaf(mv[e], fabsf(Ae[a] + Bf[c][e]), acc[a][c]);
        }
    }

    // ---- epilogue: add rank-1 terms, entmax15 closed form, diagonal ----
    float ua[8], vc[4];
    #pragma unroll
    for (int a = 0; a < 8; a++) ua[a] = ulds[ty + 16 * a];
    #pragma unroll
    for (int c = 0; c < 4; c++) vc[c] = vlds[tx + 16 * c];

    #pragma unroll
    for (int a = 0; a < 8; a++) {
        const int i = i0 + ty + 16 * a;
        #pragma unroll
        for (int c = 0; c < 4; c++) {
            float T = b2d + ua[a] + vc[c] + acc[a][c];
            float tt = T * 0.25f;
            float dd = fabsf(tt);
            float ss = sqrtf(fmaxf(0.5f - dd * dd, 0.f));
            float p0i = (ss + tt) * (ss + tt);
            float p0 = (dd >= 0.5f) ? (tt > 0.f ? 1.f : 0.f) : p0i;
            float val = fmaf(p0, w3d, w3b);
            const int j = j0 + tx + 16 * c;
            if (i == j) val = 0.f;
            out[((size_t)bk * N_ + i) * N_ + j] = val;
        }
    }
}

// ---------------------------------------------------------------------------
extern "C" void kernel_launch(void* const* d_in, const int* in_sizes, int n_in,
                              void* d_out, int out_size, void* d_ws, size_t ws_size,
                              hipStream_t stream) {
    (void)in_sizes; (void)n_in; (void)out_size; (void)ws_size;
    const float* E  = (const float*)d_in[0];
    const float* W1 = (const float*)d_in[1];
    const float* b1 = (const float*)d_in[2];
    const float* W2 = (const float*)d_in[3];
    const float* b2 = (const float*)d_in[4];
    const float* W3 = (const float*)d_in[5];
    const float* b3 = (const float*)d_in[6];
    float* out = (float*)d_out;

    char* ws = (char*)d_ws;
    float*  mW     = (float*)ws;                           // K*H f32 = 4 KB
    float*  wdaW   = (float*)(ws + 4096);                  // K*H f32 = 4 KB
    float*  consts = (float*)(ws + 8192);                  // K*4 floats
    __half* Eh     = (__half*)(ws + 12288);                // 512 KB
    __half* Wh     = (__half*)(ws + 12288 + 524288);       // 512 KB

    prep_all<<<321, 256, 0, stream>>>(E, W1, W2, b2, W3, b3, Eh, Wh, mW, wdaW, consts);
    fused_kernel<<<B_ * K_ * 8, 256, 0, stream>>>(Eh, Wh, b1, mW, wdaW, consts, out);
}